// Round 5
// baseline (235.070 us; speedup 1.0000x reference)
//
#include <hip/hip_runtime.h>

typedef float v2f __attribute__((ext_vector_type(2)));

#define IMG_W 512
#define IMG_H 512
#define RH    32            // output rows per wave
#define BW    128           // output cols per wave (2 cols/lane)
#define NW    4             // waves per workgroup (independent bands)
#define KS    11
#define KR    5
#define OFFP  9             // left pad in PAIRS; odd => 16B-aligned b128 window
#define LROWP (OFFP + BW + OFFP)     // 146 {a,b} pairs per row buffer
#define ROWS  (RH + 2 * KR)          // 42 input rows per strip
#define NPH   44                     // 4 * 11 phases (>= ROWS)

// per-row prefetch registers: RAW pixel values. OOB lanes/rows hold -1.0f,
// which the staging transform fmaf(v,0.5,0.5) maps to exactly 0.0f == conv
// zero-padding. Raw prefetch => no VALU depends on in-flight loads at issue.
struct Pf { float ax, ay, bx, by, lx, lb, rx, rb; };

// Round-5 experiment: rounds 1/3/4 all pinned at ~19% occupancy (~6 waves/CU)
// and ~130 us regardless of grid size => single-wave workgroups appear
// WG-slot/dispatch-limited, not wave-slot-limited. This version packs 4 fully
// INDEPENDENT waves per 256-thread workgroup (wave w = band w, private LDS
// ping-pong, no __syncthreads) so 4 WG slots/CU carry 16 waves/CU. Per-wave
// code is identical to round 4.
__global__ __launch_bounds__(256, 2)
void ssim_main(const float* __restrict__ xhat,
               const float* __restrict__ x,
               const float* __restrict__ kern,
               float* __restrict__ accum)
{
    __shared__ __align__(16) float lds[NW][2][2 * LROWP];  // 9.3 KB/WG

    const int lane  = threadIdx.x & 63;
    const int wv    = threadIdx.x >> 6;         // band index within image row
    const int strip = blockIdx.x & 15;          // 16 strips of 32 rows
    const int img   = blockIdx.x >> 4;
    const int base  = wv * BW;
    const int R0    = strip * RH;
    const float* xp = x    + (size_t)img * (IMG_W * IMG_H);
    const float* hp = xhat + (size_t)img * (IMG_W * IMG_H);

    // separable 1D weights from the rank-1 2D kernel
    float g[KS];
    {
        const float inv = rsqrtf(kern[5 * KS + 5]);
        #pragma unroll
        for (int i = 0; i < KS; ++i) g[i] = kern[5 * KS + i] * inv;
    }

    const int  c0   = lane << 1;
    const bool lh   = lane < KR;
    const bool rhn  = lane >= 64 - KR;
    const int  lcol = base - KR + lane;                 // lh lanes
    const int  rcol = base + BW + (lane - (64 - KR));   // rhn lanes
    const int  lidx = OFFP - KR + lane;                 // pair idx 4..8
    const int  ridx = OFFP + BW + (lane - (64 - KR));   // pair idx 137..141

    auto load_raw = [&](int rr) -> Pf {
        Pf p = {-1.f,-1.f,-1.f,-1.f,-1.f,-1.f,-1.f,-1.f};
        const int ri = R0 - KR + rr;
        if (ri >= 0 && ri < IMG_H) {
            const size_t ro = (size_t)ri * IMG_W;
            const float2 vx = *(const float2*)(xp + ro + base + c0);
            const float2 vh = *(const float2*)(hp + ro + base + c0);
            p.ax = vx.x;  p.ay = vx.y;
            p.bx = vh.x;  p.by = vh.y;
            if (lh && lcol >= 0) {
                p.lx = xp[ro + lcol];
                p.lb = hp[ro + lcol];
            }
            if (rhn && rcol < IMG_W) {
                p.rx = xp[ro + rcol];
                p.rb = hp[ro + rcol];
            }
        }
        return p;
    };

    // ring of horizontally-convolved rows: 5 fields x 11 rows x 2 cols
    v2f   h01r[KS][2];   // {sum a, sum b}
    v2f   h23r[KS][2];   // {sum a^2, sum b^2}
    float h4r [KS][2];   // sum a*b
    float acc = 0.f;
    const float C1 = 1e-4f, C2 = 9e-4f;

    Pf pfA = load_raw(0);             // even phases of current outer iter
    Pf pfB = load_raw(1);             // odd phases
    float* bufA = lds[wv][0];
    float* bufB = lds[wv][1];

    #pragma unroll 1
    for (int rblk = 0; rblk < NPH; rblk += KS) {
        #pragma unroll
        for (int p = 0; p < KS; ++p) {
            const int rr = rblk + p;            // ring slot == p (11 | rblk)
            if (rr < ROWS) {                    // wave-uniform branch
                Pf&    cur = ((p & 1) == 0) ? pfA : pfB;
                float* buf = ((p & 1) == 0) ? bufA : bufB;

                // ---- stage row rr: raw -> (v+1)/2, interleaved {a,b} ----
                *(float2*)&buf[2 * (OFFP + c0)] =
                    make_float2(fmaf(cur.ax, 0.5f, 0.5f), fmaf(cur.bx, 0.5f, 0.5f));
                *(float2*)&buf[2 * (OFFP + c0) + 2] =
                    make_float2(fmaf(cur.ay, 0.5f, 0.5f), fmaf(cur.by, 0.5f, 0.5f));
                if (lh)  *(float2*)&buf[2 * lidx] =
                    make_float2(fmaf(cur.lx, 0.5f, 0.5f), fmaf(cur.lb, 0.5f, 0.5f));
                if (rhn) *(float2*)&buf[2 * ridx] =
                    make_float2(fmaf(cur.rx, 0.5f, 0.5f), fmaf(cur.rb, 0.5f, 0.5f));

                // ---- issue raw global prefetch for row rr+2 ----
                const bool hasNext = (rr + 2 < ROWS);
                Pf nxt;
                if (hasNext) nxt = load_raw(rr + 2);

                // compiler-only ordering fence (no instruction): wave-
                // synchronous LDS is in-order per wave; backend inserts the
                // precise lgkmcnt waits. Prefetch vmcnt stays in flight.
                __asm__ __volatile__("" ::: "memory");

                // ---- horizontal pass: 6x ds_read_b128 window ----
                const float4* q = (const float4*)buf;
                float4 w[6];
                #pragma unroll
                for (int j = 0; j < 6; ++j) w[j] = q[lane + 2 + j];

                v2f h01[2] = {{0.f,0.f},{0.f,0.f}};
                v2f h23[2] = {{0.f,0.f},{0.f,0.f}};
                float h4[2] = {0.f, 0.f};
                #pragma unroll
                for (int t = 0; t < KS + 1; ++t) {
                    v2f ab;
                    ab.x = (t & 1) ? w[t >> 1].z : w[t >> 1].x;
                    ab.y = (t & 1) ? w[t >> 1].w : w[t >> 1].y;
                    const v2f  ab2 = ab * ab;
                    const float pab = ab.x * ab.y;
                    if (t < KS) {                 // tap for col 0
                        const v2f wv2 = {g[t], g[t]};
                        h01[0] = __builtin_elementwise_fma(ab,  wv2, h01[0]);
                        h23[0] = __builtin_elementwise_fma(ab2, wv2, h23[0]);
                        h4[0]  = fmaf(pab, g[t], h4[0]);
                    }
                    if (t > 0) {                  // tap for col 1
                        const v2f wv2 = {g[t - 1], g[t - 1]};
                        h01[1] = __builtin_elementwise_fma(ab,  wv2, h01[1]);
                        h23[1] = __builtin_elementwise_fma(ab2, wv2, h23[1]);
                        h4[1]  = fmaf(pab, g[t - 1], h4[1]);
                    }
                }
                #pragma unroll
                for (int c = 0; c < 2; ++c) {
                    h01r[p][c] = h01[c];
                    h23r[p][c] = h23[c];
                    h4r [p][c] = h4[c];
                }

                // ---- vertical pass + SSIM once the ring is full ----
                if (rr >= 2 * KR) {
                    v2f v01[2] = {{0.f,0.f},{0.f,0.f}};
                    v2f v23[2] = {{0.f,0.f},{0.f,0.f}};
                    float v4[2] = {0.f, 0.f};
                    #pragma unroll
                    for (int t = 0; t < KS; ++t) {
                        const int slot = (p + 1 + t) % KS;   // compile-time
                        const v2f wv2 = {g[t], g[t]};
                        #pragma unroll
                        for (int c = 0; c < 2; ++c) {
                            v01[c] = __builtin_elementwise_fma(h01r[slot][c], wv2, v01[c]);
                            v23[c] = __builtin_elementwise_fma(h23r[slot][c], wv2, v23[c]);
                            v4[c]  = fmaf(h4r[slot][c], g[t], v4[c]);
                        }
                    }
                    #pragma unroll
                    for (int c = 0; c < 2; ++c) {
                        const float mux  = v01[c].x, muy = v01[c].y;
                        const float mux2 = mux * mux;
                        const float muy2 = muy * muy;
                        const float muxy = mux * muy;
                        const float sx   = v23[c].x - mux2;
                        const float sy   = v23[c].y - muy2;
                        const float sxy  = v4[c]    - muxy;
                        const float num  = (2.f * muxy + C1) * (2.f * sxy + C2);
                        const float den  = (mux2 + muy2 + C1) * (sx + sy + C2);
                        acc = fmaf(num, __builtin_amdgcn_rcpf(den + 1e-8f), acc);
                    }
                }

                if (hasNext) cur = nxt;           // commit prefetch
            }
        }
        // 11 phases consumed (odd count): swap even/odd roles
        { Pf t = pfA; pfA = pfB; pfB = t; }
        { float* t = bufA; bufA = bufB; bufB = t; }
    }

    // per-wave shuffle reduce, one atomic per wave
    #pragma unroll
    for (int o = 32; o > 0; o >>= 1) acc += __shfl_down(acc, o, 64);
    if (lane == 0) atomicAdd(accum, acc);
}

__global__ void ssim_final(const float* __restrict__ accum,
                           float* __restrict__ out)
{
    out[0] = 1.0f - accum[0] * (1.0f / (64.0f * 512.0f * 512.0f));
}

extern "C" void kernel_launch(void* const* d_in, const int* in_sizes, int n_in,
                              void* d_out, int out_size, void* d_ws, size_t ws_size,
                              hipStream_t stream) {
    const float* xhat = (const float*)d_in[0];
    const float* xin  = (const float*)d_in[1];
    const float* kern = (const float*)d_in[2];
    float* out = (float*)d_out;
    float* ws  = (float*)d_ws;

    const int nimg = in_sizes[0] / (IMG_W * IMG_H);   // 64
    const int nblk = nimg * (IMG_H / RH);             // 64*16 = 1024 WGs x 4 waves

    hipMemsetAsync(ws, 0, sizeof(float), stream);
    ssim_main<<<nblk, 64 * NW, 0, stream>>>(xhat, xin, kern, ws);
    ssim_final<<<1, 1, 0, stream>>>(ws, out);
}